// Round 2
// baseline (490.868 us; speedup 1.0000x reference)
//
#include <hip/hip_runtime.h>
#include <hip/hip_bf16.h>
#include <math.h>

// Problem constants (N,C,H,W) = (16,128,128,128)
#define CN      128
#define HWN     16384
#define NBATCH  16
#define PLANE   (CN * HWN)
#define TSTRIDE ((size_t)NBATCH * PLANE)   // elems per tensor in kqv buf

typedef __attribute__((ext_vector_type(8))) short  short8;   // 8 bf16 = 4 VGPR
typedef __attribute__((ext_vector_type(4))) float  float4v;  // MFMA C/D

__device__ __forceinline__ unsigned short f2b(float f) {
    __hip_bfloat16 h = __float2bfloat16(f);
    return *reinterpret_cast<unsigned short*>(&h);
}
__device__ __forceinline__ unsigned packbf(float lo, float hi) {
    return (unsigned)f2b(lo) | ((unsigned)f2b(hi) << 16);
}

// ---------------------------------------------------------------------------
// Prep: weights -> bf16 wbf[o'][c] (o' = tensor*128+o, c contiguous), biases
// -> f32 bias[384].
// ---------------------------------------------------------------------------
__global__ void prep_kernel(const float* __restrict__ wk, const float* __restrict__ bk,
                            const float* __restrict__ wq, const float* __restrict__ bq,
                            const float* __restrict__ wv, const float* __restrict__ bv,
                            unsigned short* __restrict__ wbf, float* __restrict__ bias)
{
    int i = blockIdx.x * 256 + threadIdx.x;   // 0..49151
    int tensor = i >> 14, oc = i & 16383;
    const float* w = tensor == 0 ? wk : (tensor == 1 ? wq : wv);
    wbf[i] = f2b(w[oc]);
    if (i < 384) {
        const float* b = i < 128 ? bk : (i < 256 ? bq : bv);
        bias[i] = b[i & 127];
    }
}

// ---------------------------------------------------------------------------
// Phase A1: K,Q in TRANSPOSED layout [tensor][n][o][w][h].
// Block: spatial tile [h:32 x w:4] (128 positions), all 256 o-rows (K+Q).
// LDS X tile ordered s = w*32 + h so MFMA D rows = 4 consecutive h ->
// uint2 stores into [o][w][h]: per instr 16 o-rows x 32 B contiguous h.
// Grid 128 tiles/n, XCD-swizzled so the 4 w-sibling tiles sharing x cache
// lines (w-tile group of 4 = one 64B line) land on the same XCD's L2.
// ---------------------------------------------------------------------------
__global__ __launch_bounds__(256) void kq_kernel(
    const float* __restrict__ x, const unsigned short* __restrict__ wbf,
    const float* __restrict__ bias, unsigned short* __restrict__ kqv)
{
    __shared__ unsigned Xl[128 * 68];   // [s][c/2], s = wl*32+hl, 34.8 KiB

    const int bx = blockIdx.x;          // 128 spatial tiles
    const int n  = blockIdx.y;
    const int s8 = bx & 7, m4 = (bx >> 3) & 3, ht = bx >> 5;
    const int w0 = (s8 * 4 + m4) * 4;   // w-tile of 4 (same s8 -> same XCD)
    const int h0 = ht * 32;             // h-tile of 32

    const int t = threadIdx.x, lane = t & 63, wv = t >> 6;
    const int l15 = lane & 15, quad = lane >> 4;

    // ---- stage x[c][h0:+32][w0:+4] -> Xl[s][c] bf16 (s = wl*32+hl) ----
    {
        const int c0  = (t & 15) * 8;
        const int hl2 = (t >> 4) * 2;
        const float* xp = x + (size_t)n * PLANE + (size_t)c0 * HWN
                        + (h0 + hl2) * 128 + w0;
        float vv[2][8][4];
        #pragma unroll
        for (int j = 0; j < 8; ++j)
            #pragma unroll
            for (int p = 0; p < 2; ++p)
                *(float4*)vv[p][j] = *(const float4*)(xp + (size_t)j * HWN + p * 128);
        #pragma unroll
        for (int p = 0; p < 2; ++p)
            #pragma unroll
            for (int wl = 0; wl < 4; ++wl) {
                uint4 u;
                u.x = packbf(vv[p][0][wl], vv[p][1][wl]);
                u.y = packbf(vv[p][2][wl], vv[p][3][wl]);
                u.z = packbf(vv[p][4][wl], vv[p][5][wl]);
                u.w = packbf(vv[p][6][wl], vv[p][7][wl]);
                *(uint4*)&Xl[(wl * 32 + hl2 + p) * 68 + c0 / 2] = u;
            }
    }
    __syncthreads();

    // ---- B fragments (W rows): wave -> 64 o-rows of wbf[0:256) = K,Q ----
    const int ob = wv * 64;
    short8 wfr[4][4];
    #pragma unroll
    for (int nt = 0; nt < 4; ++nt)
        #pragma unroll
        for (int k = 0; k < 4; ++k)
            wfr[nt][k] = *(const short8*)&wbf[(ob + nt * 16 + l15) * CN + quad * 8 + k * 32];
    float bs[4];
    #pragma unroll
    for (int nt = 0; nt < 4; ++nt) bs[nt] = bias[ob + nt * 16 + l15];

    const int tensor = wv >> 1;          // 0 = K, 1 = Q
    const int obase  = (wv & 1) * 64;    // o within tensor

    #pragma unroll
    for (int mt = 0; mt < 8; ++mt) {
        short8 afr[4];
        #pragma unroll
        for (int k = 0; k < 4; ++k)
            afr[k] = *(const short8*)&Xl[(mt * 16 + l15) * 68 + quad * 4 + k * 16];
        const int wl = mt >> 1;
        const int hh = h0 + (mt & 1) * 16 + quad * 4;   // 4 consecutive h
        #pragma unroll
        for (int nt = 0; nt < 4; ++nt) {
            float4v acc = {bs[nt], bs[nt], bs[nt], bs[nt]};
            #pragma unroll
            for (int k = 0; k < 4; ++k)
                acc = __builtin_amdgcn_mfma_f32_16x16x32_bf16(afr[k], wfr[nt][k], acc, 0, 0, 0);
            const int o = obase + nt * 16 + l15;
            unsigned short* dst = kqv + (size_t)tensor * TSTRIDE
                                + ((size_t)n * CN + o) * HWN + (w0 + wl) * 128 + hh;
            uint2 u; u.x = packbf(acc[0], acc[1]); u.y = packbf(acc[2], acc[3]);
            *(uint2*)dst = u;
        }
    }
}

// ---------------------------------------------------------------------------
// Phase A2: V in natural layout [n][o][h][w] (GEMM2 contracts over w, needs
// w contiguous). Round-1 kqv structure restricted to the V tensor.
// ---------------------------------------------------------------------------
__global__ __launch_bounds__(256) void v_kernel(
    const float* __restrict__ x, const unsigned short* __restrict__ wbf,
    const float* __restrict__ bias, unsigned short* __restrict__ kqv)
{
    __shared__ unsigned Xl[64 * 68];   // [hw][c/2], 17 KiB

    const int n   = blockIdx.y;
    const int hw0 = blockIdx.x * 64;
    const int t = threadIdx.x, lane = t & 63, wv = t >> 6;
    const int l15 = lane & 15, quad = lane >> 4;

    {
        const int hwg = (t & 15) * 4;
        const int c0  = (t >> 4) * 8;
        const float* xp = x + (size_t)n * PLANE + (size_t)c0 * HWN + hw0 + hwg;
        float v[8][4];
        #pragma unroll
        for (int j = 0; j < 8; ++j)
            *(float4*)v[j] = *(const float4*)(xp + (size_t)j * HWN);
        #pragma unroll
        for (int jj = 0; jj < 4; ++jj) {
            uint4 u;
            u.x = packbf(v[0][jj], v[1][jj]); u.y = packbf(v[2][jj], v[3][jj]);
            u.z = packbf(v[4][jj], v[5][jj]); u.w = packbf(v[6][jj], v[7][jj]);
            *(uint4*)&Xl[(hwg + jj) * 68 + c0 / 2] = u;
        }
    }
    __syncthreads();

    short8 afr[4][4];
    #pragma unroll
    for (int mt = 0; mt < 4; ++mt)
        #pragma unroll
        for (int k = 0; k < 4; ++k)
            afr[mt][k] = *(const short8*)&Xl[(mt * 16 + l15) * 68 + quad * 4 + k * 16];

    #pragma unroll
    for (int nt = 0; nt < 2; ++nt) {
        const int ob = 256 + wv * 32 + nt * 16;   // V rows in wbf/bias
        short8 wfr[4];
        #pragma unroll
        for (int k = 0; k < 4; ++k)
            wfr[k] = *(const short8*)&wbf[(ob + l15) * CN + quad * 8 + k * 32];
        const float b = bias[ob + l15];
        const int oc = wv * 32 + nt * 16 + l15;
        unsigned short* dst = kqv + 2 * TSTRIDE + ((size_t)n * CN + oc) * HWN
                            + hw0 + quad * 4;
        #pragma unroll
        for (int mt = 0; mt < 4; ++mt) {
            float4v acc = {b, b, b, b};
            #pragma unroll
            for (int k = 0; k < 4; ++k)
                acc = __builtin_amdgcn_mfma_f32_16x16x32_bf16(afr[mt][k], wfr[k], acc, 0, 0, 0);
            uint2 u; u.x = packbf(acc[0], acc[1]); u.y = packbf(acc[2], acc[3]);
            *(uint2*)(dst + mt * 16) = u;
        }
    }
}

// ---------------------------------------------------------------------------
// Phase B: per (n,o) block (256 thr), ZERO barriers, ZERO K/Q staging:
//   GEMM1: S^T[v][w] = sum_h Q'[v][h]*K'[w][h] — fragments straight from
//          global transposed planes (16 B/lane, 64 B-coalesced segments).
//   softmax over w in registers; attn^T bf16 -> LDS (wave-private rows).
//   GEMM2: A = attn^T (own rows), B = V rows [h][w] from global.
// LDS 34 KiB (At only) -> 3-4 blocks/CU.
// ---------------------------------------------------------------------------
__global__ __launch_bounds__(256) void attn_kernel(
    const unsigned short* __restrict__ kqv, const float* __restrict__ x,
    const float* __restrict__ gamma, float* __restrict__ out)
{
    __shared__ unsigned short At[128 * 136];   // attn^T [v][w], 34 KiB

    const int no = blockIdx.x;
    const unsigned short* Kg = kqv + (size_t)no * HWN;            // [w][h]
    const unsigned short* Qg = Kg + TSTRIDE;                      // [v][h]
    const unsigned short* Vg = Kg + 2 * TSTRIDE;                  // [h][w]

    const int t = threadIdx.x, lane = t & 63, wv = t >> 6;
    const int l15 = lane & 15, quad = lane >> 4;
    const int v0 = wv * 32;

    // ---- GEMM1: wave handles v-strip of 32 (2 m-tiles x 8 n-tiles x 4 k) ----
    float4v acc1[2][8];
    #pragma unroll
    for (int mt = 0; mt < 2; ++mt)
        #pragma unroll
        for (int nt = 0; nt < 8; ++nt) acc1[mt][nt] = (float4v){0.f, 0.f, 0.f, 0.f};

    {
        short8 afr[2][4];
        #pragma unroll
        for (int mt = 0; mt < 2; ++mt)
            #pragma unroll
            for (int k = 0; k < 4; ++k)
                afr[mt][k] = *(const short8*)&Qg[(v0 + mt * 16 + l15) * 128 + quad * 8 + k * 32];
        #pragma unroll
        for (int nt = 0; nt < 8; ++nt) {
            short8 bfr[4];
            #pragma unroll
            for (int k = 0; k < 4; ++k)
                bfr[k] = *(const short8*)&Kg[(nt * 16 + l15) * 128 + quad * 8 + k * 32];
            #pragma unroll
            for (int mt = 0; mt < 2; ++mt)
                #pragma unroll
                for (int k = 0; k < 4; ++k)
                    acc1[mt][nt] = __builtin_amdgcn_mfma_f32_16x16x32_bf16(afr[mt][k], bfr[k], acc1[mt][nt], 0, 0, 0);
        }
    }

    // ---- softmax over w (rows of S^T), in registers ----
    const float sc = 0.08838834764831845f;   // 1/sqrt(128)
    #pragma unroll
    for (int mt = 0; mt < 2; ++mt)
        #pragma unroll
        for (int r = 0; r < 4; ++r) {
            float m = -INFINITY;
            #pragma unroll
            for (int nt = 0; nt < 8; ++nt) {
                acc1[mt][nt][r] *= sc;
                m = fmaxf(m, acc1[mt][nt][r]);
            }
            #pragma unroll
            for (int d = 1; d < 16; d <<= 1) m = fmaxf(m, __shfl_xor(m, d, 64));
            float s = 0.f;
            #pragma unroll
            for (int nt = 0; nt < 8; ++nt) {
                const float e = __expf(acc1[mt][nt][r] - m);
                acc1[mt][nt][r] = e;
                s += e;
            }
            #pragma unroll
            for (int d = 1; d < 16; d <<= 1) s += __shfl_xor(s, d, 64);
            const float inv = 1.0f / s;
            const int v = v0 + mt * 16 + quad * 4 + r;
            #pragma unroll
            for (int nt = 0; nt < 8; ++nt)
                At[v * 136 + nt * 16 + l15] = f2b(acc1[mt][nt][r] * inv);
        }
    // no barrier: GEMM2 reads only this wave's own At rows [v0, v0+32);
    // per-wave DS ops are in order.

    // ---- GEMM2: A = At (M = v, own strip), B = V (N = h, k = w) ----
    float4v acc2[2][8];
    #pragma unroll
    for (int mt = 0; mt < 2; ++mt)
        #pragma unroll
        for (int nt = 0; nt < 8; ++nt) acc2[mt][nt] = (float4v){0.f, 0.f, 0.f, 0.f};

    {
        short8 pfr[2][4];
        #pragma unroll
        for (int mt = 0; mt < 2; ++mt)
            #pragma unroll
            for (int k = 0; k < 4; ++k)
                pfr[mt][k] = *(const short8*)&At[(v0 + mt * 16 + l15) * 136 + quad * 8 + k * 32];
        #pragma unroll
        for (int nt = 0; nt < 8; ++nt) {
            short8 vfr[4];
            #pragma unroll
            for (int k = 0; k < 4; ++k)
                vfr[k] = *(const short8*)&Vg[(nt * 16 + l15) * 128 + quad * 8 + k * 32];
            #pragma unroll
            for (int mt = 0; mt < 2; ++mt)
                #pragma unroll
                for (int k = 0; k < 4; ++k)
                    acc2[mt][nt] = __builtin_amdgcn_mfma_f32_16x16x32_bf16(pfr[mt][k], vfr[k], acc2[mt][nt], 0, 0, 0);
        }
    }

    // ---- epilogue: out = gamma*O + x, float4 (4 consecutive v per lane) ----
    const float g = gamma[0];
    const float* xp = x + (size_t)no * HWN;
    float*       op = out + (size_t)no * HWN;
    #pragma unroll
    for (int mt = 0; mt < 2; ++mt)
        #pragma unroll
        for (int nt = 0; nt < 8; ++nt) {
            const int h    = nt * 16 + l15;
            const int vcol = v0 + mt * 16 + quad * 4;
            const int idx  = h * 128 + vcol;
            float4 xv = *(const float4*)(xp + idx);
            float4 ov;
            ov.x = fmaf(g, acc2[mt][nt][0], xv.x);
            ov.y = fmaf(g, acc2[mt][nt][1], xv.y);
            ov.z = fmaf(g, acc2[mt][nt][2], xv.z);
            ov.w = fmaf(g, acc2[mt][nt][3], xv.w);
            *(float4*)(op + idx) = ov;
        }
}

// ---------------------------------------------------------------------------
extern "C" void kernel_launch(void* const* d_in, const int* in_sizes, int n_in,
                              void* d_out, int out_size, void* d_ws, size_t ws_size,
                              hipStream_t stream) {
    const float* x     = (const float*)d_in[0];
    const float* wk    = (const float*)d_in[1];
    const float* bk    = (const float*)d_in[2];
    const float* wq    = (const float*)d_in[3];
    const float* bq    = (const float*)d_in[4];
    const float* wv    = (const float*)d_in[5];
    const float* bv    = (const float*)d_in[6];
    const float* gamma = (const float*)d_in[7];
    float* out = (float*)d_out;

    // ws: wbf bf16 (96 KiB) | bias f32 @192 KiB | kqv bf16 @256 KiB (192 MiB)
    unsigned short* wbf  = (unsigned short*)d_ws;
    float*          bias = (float*)((char*)d_ws + (192 << 10));
    unsigned short* kqv  = (unsigned short*)((char*)d_ws + (256 << 10));

    prep_kernel<<<192, 256, 0, stream>>>(wk, bk, wq, bq, wv, bv, wbf, bias);
    dim3 gK(128, NBATCH);
    kq_kernel<<<gK, 256, 0, stream>>>(x, wbf, bias, kqv);
    dim3 gV(HWN / 64, NBATCH);
    v_kernel<<<gV, 256, 0, stream>>>(x, wbf, bias, kqv);
    attn_kernel<<<NBATCH * CN, 256, 0, stream>>>(kqv, x, gamma, out);
}

// Round 4
// 473.587 us; speedup vs baseline: 1.0365x; 1.0365x over previous
//
#include <hip/hip_runtime.h>
#include <hip/hip_bf16.h>
#include <math.h>

// Problem constants (N,C,H,W) = (16,128,128,128)
#define CN      128
#define HWN     16384
#define NBATCH  16
#define PLANE   (CN * HWN)
#define TSTRIDE ((size_t)NBATCH * PLANE)   // elems per tensor in kqv buf

typedef __attribute__((ext_vector_type(8))) short  short8;   // 8 bf16 = 4 VGPR
typedef __attribute__((ext_vector_type(4))) float  float4v;  // MFMA C/D

__device__ __forceinline__ unsigned short f2b(float f) {
    __hip_bfloat16 h = __float2bfloat16(f);
    return *reinterpret_cast<unsigned short*>(&h);
}
__device__ __forceinline__ unsigned packbf(float lo, float hi) {
    return (unsigned)f2b(lo) | ((unsigned)f2b(hi) << 16);
}

// ---------------------------------------------------------------------------
// Prep: weights -> bf16 wbf[o'][c] (o' = tensor*128+o, c contiguous), biases
// -> f32 bias[384].
// ---------------------------------------------------------------------------
__global__ void prep_kernel(const float* __restrict__ wk, const float* __restrict__ bk,
                            const float* __restrict__ wq, const float* __restrict__ bq,
                            const float* __restrict__ wv, const float* __restrict__ bv,
                            unsigned short* __restrict__ wbf, float* __restrict__ bias)
{
    int i = blockIdx.x * 256 + threadIdx.x;   // 0..49151
    int tensor = i >> 14, oc = i & 16383;
    const float* w = tensor == 0 ? wk : (tensor == 1 ? wq : wv);
    wbf[i] = f2b(w[oc]);
    if (i < 384) {
        const float* b = i < 128 ? bk : (i < 256 ? bq : bv);
        bias[i] = b[i & 127];
    }
}

// ---------------------------------------------------------------------------
// Unified conv (phase A): ONE x staging per (h:16 x w:16) spatial tile serves
// all 3 tensors. LDS tile Xl[s][c] (s = h*16+w, 64 KiB, XOR-swizzled cols).
// Two fragment orderings read the same tile:
//   TRANS (K,Q): M-order w*16+h -> D rows = consecutive h -> [o][w][h] stores
//   natural (V): M-order h*16+w -> D rows = consecutive w -> [o][h][w] stores
// Tensors sequential, o in 2 groups of 64 -> acc recycled (16 float4v live).
// All stores: 16 o-rows x 32 B contiguous segments (round-1-verified shape).
// ---------------------------------------------------------------------------
__device__ __forceinline__ int swzkey(int s) { return ((s ^ (s >> 4)) & 7) << 2; }

template<bool TRANS>
__device__ __forceinline__ void conv_phase(
    const unsigned* Xl, const unsigned short* __restrict__ wbf,
    const float* __restrict__ bias, unsigned short* kqv_t,
    int tens, int h0, int w0, int wv, int l15, int quad)
{
    #pragma unroll
    for (int og = 0; og < 2; ++og) {
        float bs[4];
        #pragma unroll
        for (int ni = 0; ni < 4; ++ni)
            bs[ni] = bias[tens * 128 + og * 64 + ni * 16 + l15];

        float4v acc[4][4];
        #pragma unroll
        for (int mi = 0; mi < 4; ++mi)
            #pragma unroll
            for (int ni = 0; ni < 4; ++ni)
                acc[mi][ni] = (float4v){bs[ni], bs[ni], bs[ni], bs[ni]};

        #pragma unroll
        for (int k = 0; k < 4; ++k) {
            short8 afr[4];
            #pragma unroll
            for (int mi = 0; mi < 4; ++mi) {
                const int mt = wv * 4 + mi;
                const int s  = TRANS ? (l15 * 16 + mt) : (mt * 16 + l15);
                afr[mi] = *(const short8*)&Xl[s * 64 + ((k * 16 + quad * 4) ^ swzkey(s))];
            }
            #pragma unroll
            for (int ni = 0; ni < 4; ++ni) {
                const short8 wfr = *(const short8*)
                    &wbf[(size_t)(tens * 128 + og * 64 + ni * 16 + l15) * CN + quad * 8 + k * 32];
                #pragma unroll
                for (int mi = 0; mi < 4; ++mi)
                    acc[mi][ni] = __builtin_amdgcn_mfma_f32_16x16x32_bf16(afr[mi], wfr, acc[mi][ni], 0, 0, 0);
            }
        }

        #pragma unroll
        for (int ni = 0; ni < 4; ++ni) {
            const int o = og * 64 + ni * 16 + l15;
            unsigned short* dst0 = kqv_t + (size_t)o * HWN;
            #pragma unroll
            for (int mi = 0; mi < 4; ++mi) {
                const int mt  = wv * 4 + mi;
                const int idx = TRANS ? ((w0 + mt) * 128 + h0 + quad * 4)
                                      : ((h0 + mt) * 128 + w0 + quad * 4);
                uint2 u;
                u.x = packbf(acc[mi][ni][0], acc[mi][ni][1]);
                u.y = packbf(acc[mi][ni][2], acc[mi][ni][3]);
                *(uint2*)(dst0 + idx) = u;
            }
        }
    }
}

__global__ __launch_bounds__(256) void conv_kernel(
    const float* __restrict__ x, const unsigned short* __restrict__ wbf,
    const float* __restrict__ bias, unsigned short* __restrict__ kqv)
{
    __shared__ unsigned Xl[256 * 64];   // [s][c/2] swizzled, 64 KiB -> 2 blocks/CU

    const int n   = blockIdx.y;
    const int tid = blockIdx.x;               // 64 spatial tiles
    const int h0  = (tid >> 3) * 16, w0 = (tid & 7) * 16;

    const int th = threadIdx.x, lane = th & 63, wv = th >> 6;
    const int l15 = lane & 15, quad = lane >> 4;

    // ---- stage x[c][h0:+16][w0:+16] -> Xl (bf16, swizzled) ----
    // lanes = 16 h-rows x 4 w-quads: 16 x 64 B coalesced per instruction.
    {
        const int sh = lane & 15, swq = lane >> 4;
        const float* xp = x + (size_t)n * PLANE + (h0 + sh) * 128 + w0 + swq * 4;
        #pragma unroll
        for (int b = 0; b < 4; ++b) {
            const int cb = wv * 32 + b * 8;
            float v[8][4];
            #pragma unroll
            for (int j = 0; j < 8; ++j)
                *(float4*)v[j] = *(const float4*)(xp + (size_t)(cb + j) * HWN);
            #pragma unroll
            for (int wi = 0; wi < 4; ++wi) {
                const int s = sh * 16 + swq * 4 + wi;
                uint4 u;
                u.x = packbf(v[0][wi], v[1][wi]); u.y = packbf(v[2][wi], v[3][wi]);
                u.z = packbf(v[4][wi], v[5][wi]); u.w = packbf(v[6][wi], v[7][wi]);
                *(uint4*)&Xl[s * 64 + ((wv * 16 + b * 4) ^ swzkey(s))] = u;
            }
        }
    }
    __syncthreads();

    unsigned short* base = kqv + ((size_t)n * CN) * HWN;
    conv_phase<true >(Xl, wbf, bias, base,               0, h0, w0, wv, l15, quad);  // K
    conv_phase<true >(Xl, wbf, bias, base + TSTRIDE,     1, h0, w0, wv, l15, quad);  // Q
    conv_phase<false>(Xl, wbf, bias, base + 2 * TSTRIDE, 2, h0, w0, wv, l15, quad);  // V
}

// ---------------------------------------------------------------------------
// Phase B: per (n,o) block (256 thr), ZERO barriers, ZERO K/Q staging:
//   GEMM1: S^T[v][w] = sum_h Q'[v][h]*K'[w][h] — fragments straight from
//          global transposed planes (16 B/lane, 64 B-coalesced segments).
//   softmax over w in registers; attn^T bf16 -> LDS (wave-private rows).
//   GEMM2: A = attn^T (own rows), B = V rows [h][w] from global.
// LDS 34 KiB (At only). UNCHANGED from round 2 (verified).
// ---------------------------------------------------------------------------
__global__ __launch_bounds__(256) void attn_kernel(
    const unsigned short* __restrict__ kqv, const float* __restrict__ x,
    const float* __restrict__ gamma, float* __restrict__ out)
{
    __shared__ unsigned short At[128 * 136];   // attn^T [v][w], 34 KiB

    const int no = blockIdx.x;
    const unsigned short* Kg = kqv + (size_t)no * HWN;            // [w][h]
    const unsigned short* Qg = Kg + TSTRIDE;                      // [v][h]
    const unsigned short* Vg = Kg + 2 * TSTRIDE;                  // [h][w]

    const int t = threadIdx.x, lane = t & 63, wv = t >> 6;
    const int l15 = lane & 15, quad = lane >> 4;
    const int v0 = wv * 32;

    // ---- GEMM1: wave handles v-strip of 32 (2 m-tiles x 8 n-tiles x 4 k) ----
    float4v acc1[2][8];
    #pragma unroll
    for (int mt = 0; mt < 2; ++mt)
        #pragma unroll
        for (int nt = 0; nt < 8; ++nt) acc1[mt][nt] = (float4v){0.f, 0.f, 0.f, 0.f};

    {
        short8 afr[2][4];
        #pragma unroll
        for (int mt = 0; mt < 2; ++mt)
            #pragma unroll
            for (int k = 0; k < 4; ++k)
                afr[mt][k] = *(const short8*)&Qg[(v0 + mt * 16 + l15) * 128 + quad * 8 + k * 32];
        #pragma unroll
        for (int nt = 0; nt < 8; ++nt) {
            short8 bfr[4];
            #pragma unroll
            for (int k = 0; k < 4; ++k)
                bfr[k] = *(const short8*)&Kg[(nt * 16 + l15) * 128 + quad * 8 + k * 32];
            #pragma unroll
            for (int mt = 0; mt < 2; ++mt)
                #pragma unroll
                for (int k = 0; k < 4; ++k)
                    acc1[mt][nt] = __builtin_amdgcn_mfma_f32_16x16x32_bf16(afr[mt][k], bfr[k], acc1[mt][nt], 0, 0, 0);
        }
    }

    // ---- softmax over w (rows of S^T), in registers ----
    const float sc = 0.08838834764831845f;   // 1/sqrt(128)
    #pragma unroll
    for (int mt = 0; mt < 2; ++mt)
        #pragma unroll
        for (int r = 0; r < 4; ++r) {
            float m = -INFINITY;
            #pragma unroll
            for (int nt = 0; nt < 8; ++nt) {
                acc1[mt][nt][r] *= sc;
                m = fmaxf(m, acc1[mt][nt][r]);
            }
            #pragma unroll
            for (int d = 1; d < 16; d <<= 1) m = fmaxf(m, __shfl_xor(m, d, 64));
            float s = 0.f;
            #pragma unroll
            for (int nt = 0; nt < 8; ++nt) {
                const float e = __expf(acc1[mt][nt][r] - m);
                acc1[mt][nt][r] = e;
                s += e;
            }
            #pragma unroll
            for (int d = 1; d < 16; d <<= 1) s += __shfl_xor(s, d, 64);
            const float inv = 1.0f / s;
            const int v = v0 + mt * 16 + quad * 4 + r;
            #pragma unroll
            for (int nt = 0; nt < 8; ++nt)
                At[v * 136 + nt * 16 + l15] = f2b(acc1[mt][nt][r] * inv);
        }
    // no barrier: GEMM2 reads only this wave's own At rows [v0, v0+32);
    // per-wave DS ops are in order.

    // ---- GEMM2: A = At (M = v, own strip), B = V (N = h, k = w) ----
    float4v acc2[2][8];
    #pragma unroll
    for (int mt = 0; mt < 2; ++mt)
        #pragma unroll
        for (int nt = 0; nt < 8; ++nt) acc2[mt][nt] = (float4v){0.f, 0.f, 0.f, 0.f};

    {
        short8 pfr[2][4];
        #pragma unroll
        for (int mt = 0; mt < 2; ++mt)
            #pragma unroll
            for (int k = 0; k < 4; ++k)
                pfr[mt][k] = *(const short8*)&At[(v0 + mt * 16 + l15) * 136 + quad * 8 + k * 32];
        #pragma unroll
        for (int nt = 0; nt < 8; ++nt) {
            short8 vfr[4];
            #pragma unroll
            for (int k = 0; k < 4; ++k)
                vfr[k] = *(const short8*)&Vg[(nt * 16 + l15) * 128 + quad * 8 + k * 32];
            #pragma unroll
            for (int mt = 0; mt < 2; ++mt)
                #pragma unroll
                for (int k = 0; k < 4; ++k)
                    acc2[mt][nt] = __builtin_amdgcn_mfma_f32_16x16x32_bf16(pfr[mt][k], vfr[k], acc2[mt][nt], 0, 0, 0);
        }
    }

    // ---- epilogue: out = gamma*O + x, float4 (4 consecutive v per lane) ----
    const float g = gamma[0];
    const float* xp = x + (size_t)no * HWN;
    float*       op = out + (size_t)no * HWN;
    #pragma unroll
    for (int mt = 0; mt < 2; ++mt)
        #pragma unroll
        for (int nt = 0; nt < 8; ++nt) {
            const int h    = nt * 16 + l15;
            const int vcol = v0 + mt * 16 + quad * 4;
            const int idx  = h * 128 + vcol;
            float4 xv = *(const float4*)(xp + idx);
            float4 ov;
            ov.x = fmaf(g, acc2[mt][nt][0], xv.x);
            ov.y = fmaf(g, acc2[mt][nt][1], xv.y);
            ov.z = fmaf(g, acc2[mt][nt][2], xv.z);
            ov.w = fmaf(g, acc2[mt][nt][3], xv.w);
            *(float4*)(op + idx) = ov;
        }
}

// ---------------------------------------------------------------------------
extern "C" void kernel_launch(void* const* d_in, const int* in_sizes, int n_in,
                              void* d_out, int out_size, void* d_ws, size_t ws_size,
                              hipStream_t stream) {
    const float* x     = (const float*)d_in[0];
    const float* wk    = (const float*)d_in[1];
    const float* bk    = (const float*)d_in[2];
    const float* wq    = (const float*)d_in[3];
    const float* bq    = (const float*)d_in[4];
    const float* wv    = (const float*)d_in[5];
    const float* bv    = (const float*)d_in[6];
    const float* gamma = (const float*)d_in[7];
    float* out = (float*)d_out;

    // ws: wbf bf16 (96 KiB) | bias f32 @192 KiB | kqv bf16 @256 KiB (192 MiB)
    unsigned short* wbf  = (unsigned short*)d_ws;
    float*          bias = (float*)((char*)d_ws + (192 << 10));
    unsigned short* kqv  = (unsigned short*)((char*)d_ws + (256 << 10));

    prep_kernel<<<192, 256, 0, stream>>>(wk, bk, wq, bq, wv, bv, wbf, bias);
    dim3 gC(64, NBATCH);
    conv_kernel<<<gC, 256, 0, stream>>>(x, wbf, bias, kqv);
    attn_kernel<<<NBATCH * CN, 256, 0, stream>>>(kqv, x, gamma, out);
}